// Round 3
// baseline (503.591 us; speedup 1.0000x reference)
//
#include <hip/hip_runtime.h>
#include <hip/hip_bf16.h>

#define D_MODEL 1024
#define RANK 64
#define NCOMP 16
#define NKNOW 16384
#define TOPK 8
#define NTOK 8192   // B*S
#define CAND_CAP 128

typedef __attribute__((ext_vector_type(4))) float f32x4;
typedef __attribute__((ext_vector_type(8))) short s16x8;

static __device__ __forceinline__ unsigned short f2bf(float f) {
  union { float f; unsigned u; } v; v.f = f;
  unsigned r = v.u + 0x7FFFu + ((v.u >> 16) & 1u);
  return (unsigned short)(r >> 16);
}

// ---------------------------------------------------------------------------
// K1: T = X (8192x1024) @ B (1024x1024), where B[d][c] = cn[c>>6][d][c&63]
// 128x128 tile, 256 threads, 8x8 micro-tile, DK=16.
// ---------------------------------------------------------------------------
__global__ __launch_bounds__(256) void k1_gemm(const float* __restrict__ X,
                                               const float* __restrict__ CN,
                                               float* __restrict__ T) {
  __shared__ float As[16][132];
  __shared__ float Bs[16][132];
  const int bx = blockIdx.x & 7;        // col block 0..7
  const int by = blockIdx.x >> 3;       // row block 0..63
  const int tid = threadIdx.x;
  const int tx = tid & 15, ty = tid >> 4;
  const int row0 = by * 128, col0 = bx * 128;

  const int ar = tid >> 1;              // 0..127
  const int ac = (tid & 1) * 8;         // 0 or 8
  const float* Aptr = X + (size_t)(row0 + ar) * 1024 + ac;
  const int bd = tid >> 4;              // 0..15
  const int bc = (tid & 15) * 8;        // 0..120
  const float* Bptr = CN + (size_t)((col0 + bc) >> 6) * (1024 * 64) + bd * 64
                         + ((col0 + bc) & 63);

  float acc[8][8];
#pragma unroll
  for (int i = 0; i < 8; i++)
#pragma unroll
    for (int j = 0; j < 8; j++) acc[i][j] = 0.f;

  f32x4 a0 = *(const f32x4*)(Aptr);
  f32x4 a1 = *(const f32x4*)(Aptr + 4);
  f32x4 b0 = *(const f32x4*)(Bptr);
  f32x4 b1 = *(const f32x4*)(Bptr + 4);

  for (int k0 = 0; k0 < 1024; k0 += 16) {
    __syncthreads();
#pragma unroll
    for (int j = 0; j < 4; j++) {
      As[ac + j][ar] = a0[j];
      As[ac + 4 + j][ar] = a1[j];
    }
    *(f32x4*)&Bs[bd][bc] = b0;
    *(f32x4*)&Bs[bd][bc + 4] = b1;
    __syncthreads();
    if (k0 + 16 < 1024) {
      a0 = *(const f32x4*)(Aptr + k0 + 16);
      a1 = *(const f32x4*)(Aptr + k0 + 16 + 4);
      b0 = *(const f32x4*)(Bptr + (size_t)(k0 + 16) * 64);
      b1 = *(const f32x4*)(Bptr + (size_t)(k0 + 16) * 64 + 4);
    }
#pragma unroll
    for (int d = 0; d < 16; d++) {
      f32x4 av0 = *(const f32x4*)&As[d][ty * 8];
      f32x4 av1 = *(const f32x4*)&As[d][ty * 8 + 4];
      f32x4 bv0 = *(const f32x4*)&Bs[d][tx * 8];
      f32x4 bv1 = *(const f32x4*)&Bs[d][tx * 8 + 4];
#pragma unroll
      for (int i = 0; i < 4; i++) {
#pragma unroll
        for (int j = 0; j < 4; j++) {
          acc[i][j]         = fmaf(av0[i], bv0[j], acc[i][j]);
          acc[i][j + 4]     = fmaf(av0[i], bv1[j], acc[i][j + 4]);
          acc[i + 4][j]     = fmaf(av1[i], bv0[j], acc[i + 4][j]);
          acc[i + 4][j + 4] = fmaf(av1[i], bv1[j], acc[i + 4][j + 4]);
        }
      }
    }
  }
#pragma unroll
  for (int i = 0; i < 8; i++) {
    float* op = T + (size_t)(row0 + ty * 8 + i) * 1024 + col0 + tx * 8;
    *(f32x4*)op = *(f32x4*)&acc[i][0];
    *(f32x4*)(op + 4) = *(f32x4*)&acc[i][4];
  }
}

// ---------------------------------------------------------------------------
// K1b: Q[tok][r] = sum_n mw[tok][n] * T[tok][n*64+r]; also emit bf16 copy.
// ---------------------------------------------------------------------------
__global__ __launch_bounds__(256) void k1b_weight(const float* __restrict__ T,
                                                  const float* __restrict__ MW,
                                                  float* __restrict__ Qf,
                                                  unsigned short* __restrict__ Qb) {
  const int gid = blockIdx.x * 256 + threadIdx.x;  // 0..524287
  const int tok = gid >> 6, r = gid & 63;
  float q = 0.f;
#pragma unroll
  for (int n = 0; n < 16; n++)
    q = fmaf(MW[tok * 16 + n], T[(size_t)tok * 1024 + n * 64 + r], q);
  Qf[gid] = q;
  Qb[gid] = f2bf(q);
}

// ---------------------------------------------------------------------------
// K1c: Kb = bf16(knowledge_K)
// ---------------------------------------------------------------------------
__global__ __launch_bounds__(256) void k1c_cvt(const float* __restrict__ Kf,
                                               unsigned short* __restrict__ Kb) {
  const int gid = blockIdx.x * 256 + threadIdx.x;  // one per 4 elems
  f32x4 v = *(const f32x4*)(Kf + (size_t)gid * 4);
  unsigned short o0 = f2bf(v[0]), o1 = f2bf(v[1]), o2 = f2bf(v[2]), o3 = f2bf(v[3]);
  unsigned long long pack = (unsigned long long)o0 | ((unsigned long long)o1 << 16)
                          | ((unsigned long long)o2 << 32) | ((unsigned long long)o3 << 48);
  *(unsigned long long*)(Kb + (size_t)gid * 4) = pack;
}

// ---------------------------------------------------------------------------
// K2a: screening pass A — per-lane subset MAX only (1 fmax/score).
// Wave = (token-group tg, j-slice jsl): j in [jsl*1024,+1024), tokens tg*16..+16.
// Lane (myTok, slice) covers 256 scores; writes subMax[tok][jsl*4+slice].
// ---------------------------------------------------------------------------
__global__ __launch_bounds__(256) void k2a_max(
    const unsigned short* __restrict__ Qb,
    const unsigned short* __restrict__ Kb,
    float* __restrict__ subMax) {
  const int tid = threadIdx.x;
  const int wv = tid >> 6, lane = tid & 63;
  const int gw = blockIdx.x * 4 + wv;     // 0..8191
  const int tg = gw >> 4;                 // token group 0..511
  const int jsl = gw & 15;                // j-slice 0..15
  const int tb = tg * 16;
  const int myTok = lane & 15;
  const int slice = lane >> 4;            // 0..3

  const s16x8 bf0 = *(const s16x8*)(Qb + (size_t)(tb + myTok) * 64 + slice * 8);
  const s16x8 bf1 = *(const s16x8*)(Qb + (size_t)(tb + myTok) * 64 + 32 + slice * 8);

  const int j0 = jsl * 1024;
  const unsigned short* ap0 = Kb + (size_t)(j0 + myTok) * 64 + slice * 8;
  s16x8 af0 = *(const s16x8*)(ap0);
  s16x8 af1 = *(const s16x8*)(ap0 + 32);
  float m = -1e30f;
  for (int tt = 0; tt < 64; ++tt) {
    f32x4 c = {0.f, 0.f, 0.f, 0.f};
    c = __builtin_amdgcn_mfma_f32_16x16x32_bf16(af0, bf0, c, 0, 0, 0);
    c = __builtin_amdgcn_mfma_f32_16x16x32_bf16(af1, bf1, c, 0, 0, 0);
    if (tt + 1 < 64) {
      const unsigned short* ap = ap0 + (size_t)(tt + 1) * 16 * 64;
      af0 = *(const s16x8*)(ap);
      af1 = *(const s16x8*)(ap + 32);
    }
    m = fmaxf(m, fmaxf(fmaxf(c[0], c[1]), fmaxf(c[2], c[3])));
  }
  subMax[(size_t)(tb + myTok) * 64 + jsl * 4 + slice] = m;
}

// ---------------------------------------------------------------------------
// K2t: per-token threshold = (8th largest of 64 subset maxima) - 0.05,
// and zero the candidate counter. One wave per token.
// ---------------------------------------------------------------------------
__global__ __launch_bounds__(256) void k2t_thr(const float* __restrict__ subMax,
                                               float* __restrict__ thr,
                                               int* __restrict__ cnt) {
  const int tid = threadIdx.x;
  const int wv = tid >> 6, lane = tid & 63;
  const int tok = blockIdx.x * 4 + wv;
  float v = subMax[(size_t)tok * 64 + lane];
  float m8 = -1e30f;
#pragma unroll
  for (int e = 0; e < 8; e++) {
    float m = v;
#pragma unroll
    for (int d = 1; d < 64; d <<= 1) m = fmaxf(m, __shfl_xor(m, d));
    m8 = m;
    if (e < 7) v = (v == m) ? -1e30f : v;
  }
  if (lane == 0) {
    thr[tok] = m8 - 0.05f;
    cnt[tok] = 0;
  }
}

// ---------------------------------------------------------------------------
// K2c: screening pass C — recompute identical scores, append j where
// score >= thr[tok] (atomicAdd slot, cap CAND_CAP). Common path: 4 cmp / 2 MFMA.
// ---------------------------------------------------------------------------
__global__ __launch_bounds__(256) void k2c_compact(
    const unsigned short* __restrict__ Qb,
    const unsigned short* __restrict__ Kb,
    const float* __restrict__ thr,
    int* __restrict__ cnt, int* __restrict__ cand_idx) {
  const int tid = threadIdx.x;
  const int wv = tid >> 6, lane = tid & 63;
  const int gw = blockIdx.x * 4 + wv;
  const int tg = gw >> 4;
  const int jsl = gw & 15;
  const int tb = tg * 16;
  const int myTok = lane & 15;
  const int slice = lane >> 4;

  const s16x8 bf0 = *(const s16x8*)(Qb + (size_t)(tb + myTok) * 64 + slice * 8);
  const s16x8 bf1 = *(const s16x8*)(Qb + (size_t)(tb + myTok) * 64 + 32 + slice * 8);
  const float thrv = thr[tb + myTok];

  const int j0 = jsl * 1024;
  const unsigned short* ap0 = Kb + (size_t)(j0 + myTok) * 64 + slice * 8;
  s16x8 af0 = *(const s16x8*)(ap0);
  s16x8 af1 = *(const s16x8*)(ap0 + 32);
  for (int tt = 0; tt < 64; ++tt) {
    f32x4 c = {0.f, 0.f, 0.f, 0.f};
    c = __builtin_amdgcn_mfma_f32_16x16x32_bf16(af0, bf0, c, 0, 0, 0);
    c = __builtin_amdgcn_mfma_f32_16x16x32_bf16(af1, bf1, c, 0, 0, 0);
    if (tt + 1 < 64) {
      const unsigned short* ap = ap0 + (size_t)(tt + 1) * 16 * 64;
      af0 = *(const s16x8*)(ap);
      af1 = *(const s16x8*)(ap + 32);
    }
    const int jb = j0 + tt * 16 + slice * 4;
#pragma unroll
    for (int r = 0; r < 4; r++) {
      if (c[r] >= thrv) {
        const int slot = atomicAdd(&cnt[tb + myTok], 1);
        if (slot < CAND_CAP)
          cand_idx[(size_t)(tb + myTok) * CAND_CAP + slot] = jb + r;
      }
    }
  }
}

// ---------------------------------------------------------------------------
// K2b: one wave per token. Exact f32 rescore of cnt (<=128) candidates ->
// exact top-8 (desc score, asc idx) -> softmax -> gather V -> outputs.
// ---------------------------------------------------------------------------
__global__ __launch_bounds__(256) void k2b_select(
    const float* __restrict__ Qf, const float* __restrict__ Kf,
    const float* __restrict__ V,
    const int* __restrict__ cand_idx, const int* __restrict__ cnt,
    float* __restrict__ out, float* __restrict__ out_idx,
    float* __restrict__ out_w) {
  const int tid = threadIdx.x;
  const int wv = tid >> 6, lane = tid & 63;
  const int tok = blockIdx.x * 4 + wv;    // 0..8191

  int cn = cnt[tok];
  if (cn > CAND_CAP) cn = CAND_CAP;

  const int kc = lane >> 4;               // dim chunk 0..3
  const int cl = lane & 15;               // candidate column 0..15
  const float* qp = Qf + (size_t)tok * 64 + kc * 16;
  const f32x4 q0 = *(const f32x4*)(qp);
  const f32x4 q1 = *(const f32x4*)(qp + 4);
  const f32x4 q2 = *(const f32x4*)(qp + 8);
  const f32x4 q3 = *(const f32x4*)(qp + 12);

  float scR[8]; int jR[8];
#pragma unroll
  for (int r = 0; r < 8; r++) {
    scR[r] = -1e30f; jR[r] = 0x7fffffff;
    if (r * 16 < cn) {                    // wave-uniform branch
      const int ci = r * 16 + cl;
      const bool valid = ci < cn;
      const int j = valid ? cand_idx[(size_t)tok * CAND_CAP + ci] : 0;
      float part = 0.f;
      if (valid) {
        const float* kp = Kf + (size_t)j * 64 + kc * 16;
        const f32x4 k0 = *(const f32x4*)(kp);
        const f32x4 k1 = *(const f32x4*)(kp + 4);
        const f32x4 k2 = *(const f32x4*)(kp + 8);
        const f32x4 k3 = *(const f32x4*)(kp + 12);
#pragma unroll
        for (int e = 0; e < 4; e++) {
          part = fmaf(q0[e], k0[e], part);
          part = fmaf(q1[e], k1[e], part);
          part = fmaf(q2[e], k2[e], part);
          part = fmaf(q3[e], k3[e], part);
        }
      }
      part += __shfl_xor(part, 16);
      part += __shfl_xor(part, 32);
      if (valid) { scR[r] = part * 0.125f; jR[r] = j; }
    }
  }

  // exact top-8 (candidates replicated x4 across kc groups; tie-break dedups)
  float wsv[8]; int wjv[8];
#pragma unroll
  for (int e = 0; e < 8; e++) {
    float ms = scR[0]; int mj = jR[0];
#pragma unroll
    for (int r = 1; r < 8; r++)
      if (scR[r] > ms || (scR[r] == ms && jR[r] < mj)) { ms = scR[r]; mj = jR[r]; }
#pragma unroll
    for (int d = 1; d < 64; d <<= 1) {
      const float rs = __shfl_xor(ms, d);
      const int rj = __shfl_xor(mj, d);
      if (rs > ms || (rs == ms && rj < mj)) { ms = rs; mj = rj; }
    }
    wsv[e] = ms; wjv[e] = mj;
#pragma unroll
    for (int r = 0; r < 8; r++)
      if (jR[r] == mj) { scR[r] = -1e30f; jR[r] = 0x7fffffff; }
  }

  // softmax (redundant on all lanes)
  const float m0 = wsv[0];
  float ex[8], sum = 0.f;
#pragma unroll
  for (int r = 0; r < 8; r++) { ex[r] = expf(wsv[r] - m0); sum += ex[r]; }
  const float inv = 1.f / sum;

  if (lane == 0) {
#pragma unroll
    for (int r = 0; r < 8; r++) {
      out_idx[(size_t)tok * 8 + r] = (float)wjv[r];
      out_w[(size_t)tok * 8 + r] = ex[r] * inv;
    }
  }

  // gather V: lane owns dims [lane*16, +16)
  f32x4 a0 = {0.f,0.f,0.f,0.f}, a1 = a0, a2 = a0, a3 = a0;
#pragma unroll
  for (int r = 0; r < 8; r++) {
    const float w = ex[r] * inv;
    const float* vp = V + (size_t)wjv[r] * 1024 + lane * 16;
    const f32x4 v0 = *(const f32x4*)(vp);
    const f32x4 v1 = *(const f32x4*)(vp + 4);
    const f32x4 v2 = *(const f32x4*)(vp + 8);
    const f32x4 v3 = *(const f32x4*)(vp + 12);
    a0 += w * v0; a1 += w * v1; a2 += w * v2; a3 += w * v3;
  }
  float* op = out + (size_t)tok * 1024 + lane * 16;
  *(f32x4*)(op)      = a0;
  *(f32x4*)(op + 4)  = a1;
  *(f32x4*)(op + 8)  = a2;
  *(f32x4*)(op + 12) = a3;
}

// ---------------------------------------------------------------------------
extern "C" void kernel_launch(void* const* d_in, const int* in_sizes, int n_in,
                              void* d_out, int out_size, void* d_ws, size_t ws_size,
                              hipStream_t stream) {
  const float* x  = (const float*)d_in[0];   // [2,4096,1024]
  const float* mw = (const float*)d_in[1];   // [2,4096,16]
  const float* cn = (const float*)d_in[2];   // [16,1024,64]
  const float* kK = (const float*)d_in[3];   // [16384,64]
  const float* kV = (const float*)d_in[4];   // [16384,1024]

  float* out  = (float*)d_out;               // 8192*1024
  float* oidx = out + (size_t)NTOK * D_MODEL;       // 8192*8
  float* ow   = oidx + (size_t)NTOK * TOPK;         // 8192*8

  // workspace layout. T (33.5 MB, offsets 0..33554432) is dead after k1b;
  // the screening scratch overlays it (strictly later in the stream).
  float* T = (float*)d_ws;                                        // 33554432 B
  int*   cand_idx = (int*)d_ws;                                   // 4194304 B
  float* subMax   = (float*)((char*)d_ws + 4194304);              // 2097152 B
  float* thr      = (float*)((char*)d_ws + 6291456);              // 32768 B
  int*   cnt      = (int*)((char*)d_ws + 6324224);                // 32768 B
  float* Qf = (float*)((char*)d_ws + 33554432);                   // 2097152 B
  unsigned short* Qb = (unsigned short*)((char*)d_ws + 35651584); // 1048576 B
  unsigned short* Kb = (unsigned short*)((char*)d_ws + 36700160); // 2097152 B

  k1_gemm<<<512, 256, 0, stream>>>(x, cn, T);
  k1b_weight<<<2048, 256, 0, stream>>>(T, mw, Qf, Qb);
  k1c_cvt<<<1024, 256, 0, stream>>>(kK, Kb);
  k2a_max<<<2048, 256, 0, stream>>>(Qb, Kb, subMax);
  k2t_thr<<<2048, 256, 0, stream>>>(subMax, thr, cnt);
  k2c_compact<<<2048, 256, 0, stream>>>(Qb, Kb, thr, cnt, cand_idx);
  k2b_select<<<2048, 256, 0, stream>>>(Qf, kK, kV, cand_idx, cnt,
                                       out, oidx, ow);

  (void)in_sizes; (void)n_in; (void)out_size; (void)ws_size;
}

// Round 4
// 473.856 us; speedup vs baseline: 1.0628x; 1.0628x over previous
//
#include <hip/hip_runtime.h>
#include <hip/hip_bf16.h>

#define D_MODEL 1024
#define RANK 64
#define NCOMP 16
#define NKNOW 16384
#define TOPK 8
#define NTOK 8192   // B*S
#define MAXG 48     // candidate-group cap per token (groups of 8 j's)
#define NS 6        // rescore slots per lane (MAXG*8/64)

typedef __attribute__((ext_vector_type(4))) float f32x4;
typedef __attribute__((ext_vector_type(8))) short s16x8;

static __device__ __forceinline__ unsigned short f2bf(float f) {
  union { float f; unsigned u; } v; v.f = f;
  unsigned r = v.u + 0x7FFFu + ((v.u >> 16) & 1u);
  return (unsigned short)(r >> 16);
}
static __device__ __forceinline__ float bf2f(unsigned short h) {
  union { unsigned u; float f; } v; v.u = ((unsigned)h) << 16;
  return v.f;
}

// ---------------------------------------------------------------------------
// K1: T = X (8192x1024) @ B (1024x1024), B[d][c] = cn[c>>6][d][c&63].
// 128x128 tile, 256 threads, 8x8 micro-tile, K-step 32.
// LDS layout swizzle: logical col c -> phys (c>>3)*12 + (c&7)  (chunk of 8
// padded to 12 floats = 48B: keeps 16B alignment for b128 reads, spreads the
// 16 chunk-starts over banks with only free 2-way aliasing).
// ---------------------------------------------------------------------------
__global__ __launch_bounds__(256) void k1_gemm(const float* __restrict__ X,
                                               const float* __restrict__ CN,
                                               float* __restrict__ T) {
  __shared__ float As[32][192];
  __shared__ float Bs[32][192];
  const int bx = blockIdx.x & 7;        // col block 0..7
  const int by = blockIdx.x >> 3;       // row block 0..63
  const int tid = threadIdx.x;
  const int tx = tid & 15, ty = tid >> 4;
  const int row0 = by * 128, col0 = bx * 128;

  // A staging: thread -> row ar, k-halves ak..ak+15
  const int ar = tid >> 1;              // 0..127
  const int ak = (tid & 1) * 16;        // 0 or 16
  const float* Aptr = X + (size_t)(row0 + ar) * 1024 + ak;
  const int apc = (ar >> 3) * 12 + (ar & 7);   // phys col of row ar

  // B staging: thread -> col chunk bc..bc+7, k rows bkk, bkk+1
  const int bc = tx * 8;
  const int bkk = ty * 2;               // 0..30
  const float* Bptr = CN + (size_t)((col0 + bc) >> 6) * (1024 * 64) + bkk * 64
                         + ((col0 + bc) & 63);
  const int bpc = tx * 12;              // phys col of chunk tx

  float acc[8][8] = {};

  f32x4 a0 = *(const f32x4*)(Aptr);
  f32x4 a1 = *(const f32x4*)(Aptr + 4);
  f32x4 a2 = *(const f32x4*)(Aptr + 8);
  f32x4 a3 = *(const f32x4*)(Aptr + 12);
  f32x4 b0 = *(const f32x4*)(Bptr);
  f32x4 b1 = *(const f32x4*)(Bptr + 4);
  f32x4 b2 = *(const f32x4*)(Bptr + 64);
  f32x4 b3 = *(const f32x4*)(Bptr + 68);

  for (int k0 = 0; k0 < 1024; k0 += 32) {
    __syncthreads();
#pragma unroll
    for (int e = 0; e < 4; e++) {
      As[ak + e][apc]      = a0[e];
      As[ak + 4 + e][apc]  = a1[e];
      As[ak + 8 + e][apc]  = a2[e];
      As[ak + 12 + e][apc] = a3[e];
    }
    *(f32x4*)&Bs[bkk][bpc]         = b0;
    *(f32x4*)&Bs[bkk][bpc + 4]     = b1;
    *(f32x4*)&Bs[bkk + 1][bpc]     = b2;
    *(f32x4*)&Bs[bkk + 1][bpc + 4] = b3;
    __syncthreads();
    if (k0 + 32 < 1024) {
      const float* An = Aptr + k0 + 32;
      a0 = *(const f32x4*)(An);
      a1 = *(const f32x4*)(An + 4);
      a2 = *(const f32x4*)(An + 8);
      a3 = *(const f32x4*)(An + 12);
      const float* Bn = Bptr + (size_t)(k0 + 32) * 64;
      b0 = *(const f32x4*)(Bn);
      b1 = *(const f32x4*)(Bn + 4);
      b2 = *(const f32x4*)(Bn + 64);
      b3 = *(const f32x4*)(Bn + 68);
    }
#pragma unroll
    for (int d = 0; d < 32; d++) {
      const f32x4 av0 = *(const f32x4*)&As[d][ty * 12];
      const f32x4 av1 = *(const f32x4*)&As[d][ty * 12 + 4];
      const f32x4 bv0 = *(const f32x4*)&Bs[d][tx * 12];
      const f32x4 bv1 = *(const f32x4*)&Bs[d][tx * 12 + 4];
#pragma unroll
      for (int i = 0; i < 4; i++) {
#pragma unroll
        for (int j = 0; j < 4; j++) {
          acc[i][j]         = fmaf(av0[i], bv0[j], acc[i][j]);
          acc[i][j + 4]     = fmaf(av0[i], bv1[j], acc[i][j + 4]);
          acc[i + 4][j]     = fmaf(av1[i], bv0[j], acc[i + 4][j]);
          acc[i + 4][j + 4] = fmaf(av1[i], bv1[j], acc[i + 4][j + 4]);
        }
      }
    }
  }
#pragma unroll
  for (int i = 0; i < 8; i++) {
    float* op = T + (size_t)(row0 + ty * 8 + i) * 1024 + col0 + tx * 8;
    *(f32x4*)op = *(f32x4*)&acc[i][0];
    *(f32x4*)(op + 4) = *(f32x4*)&acc[i][4];
  }
}

// ---------------------------------------------------------------------------
// K1b: Q[tok][r] = sum_n mw[tok][n] * T[tok][n*64+r]; also emit bf16 copy.
// ---------------------------------------------------------------------------
__global__ __launch_bounds__(256) void k1b_weight(const float* __restrict__ T,
                                                  const float* __restrict__ MW,
                                                  float* __restrict__ Qf,
                                                  unsigned short* __restrict__ Qb) {
  const int gid = blockIdx.x * 256 + threadIdx.x;  // 0..524287
  const int tok = gid >> 6, r = gid & 63;
  float q = 0.f;
#pragma unroll
  for (int n = 0; n < 16; n++)
    q = fmaf(MW[tok * 16 + n], T[(size_t)tok * 1024 + n * 64 + r], q);
  Qf[gid] = q;
  Qb[gid] = f2bf(q);
}

// ---------------------------------------------------------------------------
// K1c: Kb = bf16(knowledge_K)
// ---------------------------------------------------------------------------
__global__ __launch_bounds__(256) void k1c_cvt(const float* __restrict__ Kf,
                                               unsigned short* __restrict__ Kb) {
  const int gid = blockIdx.x * 256 + threadIdx.x;  // one per 4 elems
  f32x4 v = *(const f32x4*)(Kf + (size_t)gid * 4);
  unsigned short o0 = f2bf(v[0]), o1 = f2bf(v[1]), o2 = f2bf(v[2]), o3 = f2bf(v[3]);
  unsigned long long pack = (unsigned long long)o0 | ((unsigned long long)o1 << 16)
                          | ((unsigned long long)o2 << 32) | ((unsigned long long)o3 << 48);
  *(unsigned long long*)(Kb + (size_t)gid * 4) = pack;
}

// ---------------------------------------------------------------------------
// K2s: SINGLE screening pass. Per lane/tt: gm4 = max(c[0..3]); pair slices
// via shfl_xor(16) -> group-of-8 max; store bf16 to GM[tok][2048].
// ---------------------------------------------------------------------------
__global__ __launch_bounds__(256) void k2s_screen(
    const unsigned short* __restrict__ Qb,
    const unsigned short* __restrict__ Kb,
    unsigned short* __restrict__ GM) {
  const int tid = threadIdx.x;
  const int wv = tid >> 6, lane = tid & 63;
  const int gw = blockIdx.x * 4 + wv;     // 0..8191
  const int tg = gw >> 4;                 // token group 0..511
  const int jsl = gw & 15;                // j-slice 0..15
  const int tb = tg * 16;
  const int myTok = lane & 15;
  const int slice = lane >> 4;            // 0..3

  const s16x8 bf0 = *(const s16x8*)(Qb + (size_t)(tb + myTok) * 64 + slice * 8);
  const s16x8 bf1 = *(const s16x8*)(Qb + (size_t)(tb + myTok) * 64 + 32 + slice * 8);

  const int j0 = jsl * 1024;
  const unsigned short* ap0 = Kb + (size_t)(j0 + myTok) * 64 + slice * 8;
  s16x8 af0 = *(const s16x8*)(ap0);
  s16x8 af1 = *(const s16x8*)(ap0 + 32);

  // group id for (jsl,tt,slice): jsl*128 + tt*2 + (slice>>1)
  unsigned short* gp = GM + (size_t)(tb + myTok) * 2048 + jsl * 128 + (slice >> 1);
  const bool writer = (slice & 1) == 0;

  for (int tt = 0; tt < 64; ++tt) {
    f32x4 c = {0.f, 0.f, 0.f, 0.f};
    c = __builtin_amdgcn_mfma_f32_16x16x32_bf16(af0, bf0, c, 0, 0, 0);
    c = __builtin_amdgcn_mfma_f32_16x16x32_bf16(af1, bf1, c, 0, 0, 0);
    if (tt + 1 < 64) {
      const unsigned short* ap = ap0 + (size_t)(tt + 1) * 16 * 64;
      af0 = *(const s16x8*)(ap);
      af1 = *(const s16x8*)(ap + 32);
    }
    const float gm4 = fmaxf(fmaxf(c[0], c[1]), fmaxf(c[2], c[3]));
    const float gm8 = fmaxf(gm4, __shfl_xor(gm4, 16));
    if (writer) gp[tt * 2] = f2bf(gm8);
  }
}

// ---------------------------------------------------------------------------
// K2b: one wave per token. Read 2048 group-maxima -> thr = 8th-largest
// lane-max - margin (>=8 groups guaranteed) -> compact candidate groups ->
// exact f32 rescore of <=MAXG*8 j's -> exact top-8 (desc score, asc idx) ->
// softmax -> gather V -> outputs.
// ---------------------------------------------------------------------------
__global__ __launch_bounds__(256) void k2b_select(
    const float* __restrict__ Qf, const float* __restrict__ Kf,
    const float* __restrict__ V, const unsigned short* __restrict__ GM,
    float* __restrict__ out, float* __restrict__ out_idx,
    float* __restrict__ out_w) {
  __shared__ float qsh[4][64];
  __shared__ int csh[4][MAXG];
  __shared__ int scnt[4];
  const int tid = threadIdx.x;
  const int wv = tid >> 6, lane = tid & 63;
  const int tok = blockIdx.x * 4 + wv;    // 0..8191

  if (lane == 0) scnt[wv] = 0;
  qsh[wv][lane] = Qf[(size_t)tok * 64 + lane];

  // load 32 group-maxima per lane: groups g = i*256 + lane*4 + e
  unsigned long long gv[8];
  const unsigned long long* gmp =
      (const unsigned long long*)(GM + (size_t)tok * 2048);
#pragma unroll
  for (int i = 0; i < 8; i++) gv[i] = gmp[i * 64 + lane];

  float lm = -1e30f;
#pragma unroll
  for (int i = 0; i < 8; i++)
#pragma unroll
    for (int e = 0; e < 4; e++)
      lm = fmaxf(lm, bf2f((unsigned short)(gv[i] >> (e * 16))));

  // 8th-largest of the 64 lane-maxima (ties drop together -> thr only lower)
  float v = lm, m8 = -1e30f;
#pragma unroll
  for (int e = 0; e < 8; e++) {
    float m = v;
#pragma unroll
    for (int d = 1; d < 64; d <<= 1) m = fmaxf(m, __shfl_xor(m, d));
    m8 = m;
    if (e < 7) v = (v == m) ? -1e30f : v;
  }
  const float thr = m8 - 0.04f;

  // compact candidate groups (order irrelevant: exact rescore decides)
#pragma unroll
  for (int i = 0; i < 8; i++) {
#pragma unroll
    for (int e = 0; e < 4; e++) {
      const float g = bf2f((unsigned short)(gv[i] >> (e * 16)));
      if (g >= thr) {
        const int s = atomicAdd(&scnt[wv], 1);
        if (s < MAXG) csh[wv][s] = i * 256 + lane * 4 + e;
      }
    }
  }
  int ng = scnt[wv];
  if (ng > MAXG) ng = MAXG;
  const int nj = ng * 8;

  // exact f32 rescore
  float scR[NS]; int jR[NS];
#pragma unroll
  for (int s = 0; s < NS; s++) {
    scR[s] = -1e30f; jR[s] = 0x7fffffff;
    if (s * 64 < nj) {                    // wave-uniform
      const int ci = s * 64 + lane;
      if (ci < nj) {
        const int j = csh[wv][ci >> 3] * 8 + (ci & 7);
        const float* kp = Kf + (size_t)j * 64;
        float acc = 0.f;
#pragma unroll
        for (int k = 0; k < 64; k += 4) {
          const f32x4 qv = *(const f32x4*)&qsh[wv][k];
          const f32x4 kv = *(const f32x4*)(kp + k);
          acc = fmaf(qv[0], kv[0], acc);
          acc = fmaf(qv[1], kv[1], acc);
          acc = fmaf(qv[2], kv[2], acc);
          acc = fmaf(qv[3], kv[3], acc);
        }
        scR[s] = acc * 0.125f; jR[s] = j;
      }
    }
  }

  // exact top-8 (desc score, asc idx)
  float wsv[8]; int wjv[8];
#pragma unroll
  for (int e = 0; e < 8; e++) {
    float ms = scR[0]; int mj = jR[0];
#pragma unroll
    for (int s = 1; s < NS; s++)
      if (scR[s] > ms || (scR[s] == ms && jR[s] < mj)) { ms = scR[s]; mj = jR[s]; }
#pragma unroll
    for (int d = 1; d < 64; d <<= 1) {
      const float rs = __shfl_xor(ms, d);
      const int rj = __shfl_xor(mj, d);
      if (rs > ms || (rs == ms && rj < mj)) { ms = rs; mj = rj; }
    }
    wsv[e] = ms; wjv[e] = mj;
#pragma unroll
    for (int s = 0; s < NS; s++)
      if (jR[s] == mj) { scR[s] = -1e30f; jR[s] = 0x7fffffff; }
  }

  // softmax (redundant on all lanes)
  const float m0 = wsv[0];
  float ex[8], sum = 0.f;
#pragma unroll
  for (int r = 0; r < 8; r++) { ex[r] = expf(wsv[r] - m0); sum += ex[r]; }
  const float inv = 1.f / sum;

  if (lane == 0) {
#pragma unroll
    for (int r = 0; r < 8; r++) {
      out_idx[(size_t)tok * 8 + r] = (float)wjv[r];
      out_w[(size_t)tok * 8 + r] = ex[r] * inv;
    }
  }

  // gather V: lane owns dims [lane*16, +16)
  f32x4 a0 = {0.f,0.f,0.f,0.f}, a1 = a0, a2 = a0, a3 = a0;
#pragma unroll
  for (int r = 0; r < 8; r++) {
    const float w = ex[r] * inv;
    const float* vp = V + (size_t)wjv[r] * 1024 + lane * 16;
    const f32x4 v0 = *(const f32x4*)(vp);
    const f32x4 v1 = *(const f32x4*)(vp + 4);
    const f32x4 v2 = *(const f32x4*)(vp + 8);
    const f32x4 v3 = *(const f32x4*)(vp + 12);
    a0 += w * v0; a1 += w * v1; a2 += w * v2; a3 += w * v3;
  }
  float* op = out + (size_t)tok * 1024 + lane * 16;
  *(f32x4*)(op)      = a0;
  *(f32x4*)(op + 4)  = a1;
  *(f32x4*)(op + 8)  = a2;
  *(f32x4*)(op + 12) = a3;
}

// ---------------------------------------------------------------------------
extern "C" void kernel_launch(void* const* d_in, const int* in_sizes, int n_in,
                              void* d_out, int out_size, void* d_ws, size_t ws_size,
                              hipStream_t stream) {
  const float* x  = (const float*)d_in[0];   // [2,4096,1024]
  const float* mw = (const float*)d_in[1];   // [2,4096,16]
  const float* cn = (const float*)d_in[2];   // [16,1024,64]
  const float* kK = (const float*)d_in[3];   // [16384,64]
  const float* kV = (const float*)d_in[4];   // [16384,1024]

  float* out  = (float*)d_out;               // 8192*1024
  float* oidx = out + (size_t)NTOK * D_MODEL;       // 8192*8
  float* ow   = oidx + (size_t)NTOK * TOPK;         // 8192*8

  // workspace: T (32MiB) is dead after k1b; GM (8192*2048*2B = 32MiB) overlays it.
  float* T = (float*)d_ws;                                        // 33554432 B
  unsigned short* GM = (unsigned short*)d_ws;                     // 33554432 B
  float* Qf = (float*)((char*)d_ws + 33554432);                   // 2097152 B
  unsigned short* Qb = (unsigned short*)((char*)d_ws + 35651584); // 1048576 B
  unsigned short* Kb = (unsigned short*)((char*)d_ws + 36700160); // 2097152 B

  k1_gemm<<<512, 256, 0, stream>>>(x, cn, T);
  k1b_weight<<<2048, 256, 0, stream>>>(T, mw, Qf, Qb);
  k1c_cvt<<<1024, 256, 0, stream>>>(kK, Kb);
  k2s_screen<<<2048, 256, 0, stream>>>(Qb, Kb, GM);
  k2b_select<<<2048, 256, 0, stream>>>(Qf, kK, kV, GM, out, oidx, ow);

  (void)in_sizes; (void)n_in; (void)out_size; (void)ws_size;
}

// Round 5
// 431.967 us; speedup vs baseline: 1.1658x; 1.0970x over previous
//
#include <hip/hip_runtime.h>
#include <hip/hip_bf16.h>

#define D_MODEL 1024
#define RANK 64
#define NCOMP 16
#define NKNOW 16384
#define TOPK 8
#define NTOK 8192   // B*S
#define MAXG 48     // candidate-group cap per token (groups of 8 j's)
#define NS 6        // rescore slots per lane (MAXG*8/64)

typedef __attribute__((ext_vector_type(4))) float f32x4;
typedef __attribute__((ext_vector_type(8))) short s16x8;

static __device__ __forceinline__ unsigned short f2bf(float f) {
  union { float f; unsigned u; } v; v.f = f;
  unsigned r = v.u + 0x7FFFu + ((v.u >> 16) & 1u);
  return (unsigned short)(r >> 16);
}
static __device__ __forceinline__ float bf2f(unsigned short h) {
  union { unsigned u; float f; } v; v.u = ((unsigned)h) << 16;
  return v.f;
}

// ---------------------------------------------------------------------------
// K1: T_part[ks] = X(8192 x kl) @ B(kl x 1024) over K rows [ks*kl, +kl),
// B[d][c] = cn[c>>6][d][c&63]. 128x128 tile, 256 threads, 8x8 micro, K-step 16.
// LDS swizzle: logical col c -> phys (c>>3)*12 + (c&7). 48B chunk pitch keeps
// 16B alignment for b128 and spreads the 16 read-start positions over 8 bank
// quads (2-way aliasing = free). Row stride 192 floats.
// ---------------------------------------------------------------------------
__global__ __launch_bounds__(256) void k1_gemm(const float* __restrict__ X,
                                               const float* __restrict__ CN,
                                               float* __restrict__ T,
                                               int kl) {
  __shared__ float As[16][192];
  __shared__ float Bs[16][192];
  const int bid = blockIdx.x & 511;
  const int ks = blockIdx.x >> 9;       // K-part
  const int bx = bid & 7;               // col block 0..7
  const int by = bid >> 3;              // row block 0..63
  const int tid = threadIdx.x;
  const int tx = tid & 15, ty = tid >> 4;
  const int row0 = by * 128, col0 = bx * 128;
  const int kbeg = ks * kl, kend = kbeg + kl;
  T += (size_t)ks * (8192 * 1024);

  // A staging: thread -> row ar, k-cols (k0+ac)..+7
  const int ar = tid >> 1;              // 0..127
  const int ac = (tid & 1) * 8;         // 0 or 8
  const float* Aptr = X + (size_t)(row0 + ar) * 1024 + ac;
  const int apc = (ar >> 3) * 12 + (ar & 7);   // phys col of row ar

  // B staging: thread -> k-row bd, col chunk bc..bc+7 (never straddles n)
  const int bd = tid >> 4;              // 0..15
  const int bc = (tid & 15) * 8;        // 0..120
  const float* Bptr = CN + (size_t)((col0 + bc) >> 6) * (1024 * 64) + bd * 64
                         + ((col0 + bc) & 63);
  const int bpc = (tid & 15) * 12;      // phys col of chunk

  float acc[8][8] = {};

  f32x4 a0 = *(const f32x4*)(Aptr + kbeg);
  f32x4 a1 = *(const f32x4*)(Aptr + kbeg + 4);
  f32x4 b0 = *(const f32x4*)(Bptr + (size_t)kbeg * 64);
  f32x4 b1 = *(const f32x4*)(Bptr + (size_t)kbeg * 64 + 4);

  for (int k0 = kbeg; k0 < kend; k0 += 16) {
    __syncthreads();
#pragma unroll
    for (int j = 0; j < 4; j++) {
      As[ac + j][apc] = a0[j];
      As[ac + 4 + j][apc] = a1[j];
    }
    *(f32x4*)&Bs[bd][bpc] = b0;
    *(f32x4*)&Bs[bd][bpc + 4] = b1;
    __syncthreads();
    if (k0 + 16 < kend) {
      a0 = *(const f32x4*)(Aptr + k0 + 16);
      a1 = *(const f32x4*)(Aptr + k0 + 16 + 4);
      b0 = *(const f32x4*)(Bptr + (size_t)(k0 + 16) * 64);
      b1 = *(const f32x4*)(Bptr + (size_t)(k0 + 16) * 64 + 4);
    }
#pragma unroll
    for (int d = 0; d < 16; d++) {
      const f32x4 av0 = *(const f32x4*)&As[d][ty * 12];
      const f32x4 av1 = *(const f32x4*)&As[d][ty * 12 + 4];
      const f32x4 bv0 = *(const f32x4*)&Bs[d][tx * 12];
      const f32x4 bv1 = *(const f32x4*)&Bs[d][tx * 12 + 4];
#pragma unroll
      for (int i = 0; i < 4; i++) {
#pragma unroll
        for (int j = 0; j < 4; j++) {
          acc[i][j]         = fmaf(av0[i], bv0[j], acc[i][j]);
          acc[i][j + 4]     = fmaf(av0[i], bv1[j], acc[i][j + 4]);
          acc[i + 4][j]     = fmaf(av1[i], bv0[j], acc[i + 4][j]);
          acc[i + 4][j + 4] = fmaf(av1[i], bv1[j], acc[i + 4][j + 4]);
        }
      }
    }
  }
#pragma unroll
  for (int i = 0; i < 8; i++) {
    float* op = T + (size_t)(row0 + ty * 8 + i) * 1024 + col0 + tx * 8;
    *(f32x4*)op = *(f32x4*)&acc[i][0];
    *(f32x4*)(op + 4) = *(f32x4*)&acc[i][4];
  }
}

// ---------------------------------------------------------------------------
// K1b: Q[tok][r] = sum_n mw[tok][n] * (T0+T1)[tok][n*64+r]; emit bf16 copy.
// ---------------------------------------------------------------------------
__global__ __launch_bounds__(256) void k1b_weight(const float* __restrict__ T,
                                                  const float* __restrict__ MW,
                                                  float* __restrict__ Qf,
                                                  unsigned short* __restrict__ Qb,
                                                  int kparts) {
  const int gid = blockIdx.x * 256 + threadIdx.x;  // 0..524287
  const int tok = gid >> 6, r = gid & 63;
  float q = 0.f;
#pragma unroll
  for (int n = 0; n < 16; n++) {
    float tv = T[(size_t)tok * 1024 + n * 64 + r];
    if (kparts == 2)
      tv += T[(size_t)(8192 * 1024) + (size_t)tok * 1024 + n * 64 + r];
    q = fmaf(MW[tok * 16 + n], tv, q);
  }
  Qf[gid] = q;
  Qb[gid] = f2bf(q);
}

// ---------------------------------------------------------------------------
// K1c: Kb = bf16(knowledge_K)
// ---------------------------------------------------------------------------
__global__ __launch_bounds__(256) void k1c_cvt(const float* __restrict__ Kf,
                                               unsigned short* __restrict__ Kb) {
  const int gid = blockIdx.x * 256 + threadIdx.x;  // one per 4 elems
  f32x4 v = *(const f32x4*)(Kf + (size_t)gid * 4);
  unsigned short o0 = f2bf(v[0]), o1 = f2bf(v[1]), o2 = f2bf(v[2]), o3 = f2bf(v[3]);
  unsigned long long pack = (unsigned long long)o0 | ((unsigned long long)o1 << 16)
                          | ((unsigned long long)o2 << 32) | ((unsigned long long)o3 << 48);
  *(unsigned long long*)(Kb + (size_t)gid * 4) = pack;
}

// ---------------------------------------------------------------------------
// K2s: SINGLE screening pass. Per lane/tt: gm4 = max(c[0..3]); pair slices
// via shfl_xor(16) -> group-of-8 max; store bf16 to GM[tok][2048].
// ---------------------------------------------------------------------------
__global__ __launch_bounds__(256) void k2s_screen(
    const unsigned short* __restrict__ Qb,
    const unsigned short* __restrict__ Kb,
    unsigned short* __restrict__ GM) {
  const int tid = threadIdx.x;
  const int wv = tid >> 6, lane = tid & 63;
  const int gw = blockIdx.x * 4 + wv;     // 0..8191
  const int tg = gw >> 4;                 // token group 0..511
  const int jsl = gw & 15;                // j-slice 0..15
  const int tb = tg * 16;
  const int myTok = lane & 15;
  const int slice = lane >> 4;            // 0..3

  const s16x8 bf0 = *(const s16x8*)(Qb + (size_t)(tb + myTok) * 64 + slice * 8);
  const s16x8 bf1 = *(const s16x8*)(Qb + (size_t)(tb + myTok) * 64 + 32 + slice * 8);

  const int j0 = jsl * 1024;
  const unsigned short* ap0 = Kb + (size_t)(j0 + myTok) * 64 + slice * 8;
  s16x8 af0 = *(const s16x8*)(ap0);
  s16x8 af1 = *(const s16x8*)(ap0 + 32);

  // group id for (jsl,tt,slice): jsl*128 + tt*2 + (slice>>1)
  unsigned short* gp = GM + (size_t)(tb + myTok) * 2048 + jsl * 128 + (slice >> 1);
  const bool writer = (slice & 1) == 0;

  for (int tt = 0; tt < 64; ++tt) {
    f32x4 c = {0.f, 0.f, 0.f, 0.f};
    c = __builtin_amdgcn_mfma_f32_16x16x32_bf16(af0, bf0, c, 0, 0, 0);
    c = __builtin_amdgcn_mfma_f32_16x16x32_bf16(af1, bf1, c, 0, 0, 0);
    if (tt + 1 < 64) {
      const unsigned short* ap = ap0 + (size_t)(tt + 1) * 16 * 64;
      af0 = *(const s16x8*)(ap);
      af1 = *(const s16x8*)(ap + 32);
    }
    const float gm4 = fmaxf(fmaxf(c[0], c[1]), fmaxf(c[2], c[3]));
    const float gm8 = fmaxf(gm4, __shfl_xor(gm4, 16));
    if (writer) gp[tt * 2] = f2bf(gm8);
  }
}

// ---------------------------------------------------------------------------
// K2b: one wave per token. Read 2048 group-maxima -> thr = 8th-largest
// lane-max - margin (>=8 groups guaranteed) -> compact candidate groups ->
// exact f32 rescore of <=MAXG*8 j's -> exact top-8 (desc score, asc idx) ->
// softmax -> gather V -> outputs.
// ---------------------------------------------------------------------------
__global__ __launch_bounds__(256) void k2b_select(
    const float* __restrict__ Qf, const float* __restrict__ Kf,
    const float* __restrict__ V, const unsigned short* __restrict__ GM,
    float* __restrict__ out, float* __restrict__ out_idx,
    float* __restrict__ out_w) {
  __shared__ float qsh[4][64];
  __shared__ int csh[4][MAXG];
  __shared__ int scnt[4];
  const int tid = threadIdx.x;
  const int wv = tid >> 6, lane = tid & 63;
  const int tok = blockIdx.x * 4 + wv;    // 0..8191

  if (lane == 0) scnt[wv] = 0;
  qsh[wv][lane] = Qf[(size_t)tok * 64 + lane];

  // load 32 group-maxima per lane: groups g = i*256 + lane*4 + e
  unsigned long long gv[8];
  const unsigned long long* gmp =
      (const unsigned long long*)(GM + (size_t)tok * 2048);
#pragma unroll
  for (int i = 0; i < 8; i++) gv[i] = gmp[i * 64 + lane];

  float lm = -1e30f;
#pragma unroll
  for (int i = 0; i < 8; i++)
#pragma unroll
    for (int e = 0; e < 4; e++)
      lm = fmaxf(lm, bf2f((unsigned short)(gv[i] >> (e * 16))));

  // 8th-largest of the 64 lane-maxima (ties drop together -> thr only lower)
  float v = lm, m8 = -1e30f;
#pragma unroll
  for (int e = 0; e < 8; e++) {
    float m = v;
#pragma unroll
    for (int d = 1; d < 64; d <<= 1) m = fmaxf(m, __shfl_xor(m, d));
    m8 = m;
    if (e < 7) v = (v == m) ? -1e30f : v;
  }
  const float thr = m8 - 0.04f;

  // compact candidate groups (order irrelevant: exact rescore decides)
#pragma unroll
  for (int i = 0; i < 8; i++) {
#pragma unroll
    for (int e = 0; e < 4; e++) {
      const float g = bf2f((unsigned short)(gv[i] >> (e * 16)));
      if (g >= thr) {
        const int s = atomicAdd(&scnt[wv], 1);
        if (s < MAXG) csh[wv][s] = i * 256 + lane * 4 + e;
      }
    }
  }
  int ng = scnt[wv];
  if (ng > MAXG) ng = MAXG;
  const int nj = ng * 8;

  // exact f32 rescore
  float scR[NS]; int jR[NS];
#pragma unroll
  for (int s = 0; s < NS; s++) {
    scR[s] = -1e30f; jR[s] = 0x7fffffff;
    if (s * 64 < nj) {                    // wave-uniform
      const int ci = s * 64 + lane;
      if (ci < nj) {
        const int j = csh[wv][ci >> 3] * 8 + (ci & 7);
        const float* kp = Kf + (size_t)j * 64;
        float acc = 0.f;
#pragma unroll
        for (int k = 0; k < 64; k += 4) {
          const f32x4 qv = *(const f32x4*)&qsh[wv][k];
          const f32x4 kv = *(const f32x4*)(kp + k);
          acc = fmaf(qv[0], kv[0], acc);
          acc = fmaf(qv[1], kv[1], acc);
          acc = fmaf(qv[2], kv[2], acc);
          acc = fmaf(qv[3], kv[3], acc);
        }
        scR[s] = acc * 0.125f; jR[s] = j;
      }
    }
  }

  // exact top-8 (desc score, asc idx)
  float wsv[8]; int wjv[8];
#pragma unroll
  for (int e = 0; e < 8; e++) {
    float ms = scR[0]; int mj = jR[0];
#pragma unroll
    for (int s = 1; s < NS; s++)
      if (scR[s] > ms || (scR[s] == ms && jR[s] < mj)) { ms = scR[s]; mj = jR[s]; }
#pragma unroll
    for (int d = 1; d < 64; d <<= 1) {
      const float rs = __shfl_xor(ms, d);
      const int rj = __shfl_xor(mj, d);
      if (rs > ms || (rs == ms && rj < mj)) { ms = rs; mj = rj; }
    }
    wsv[e] = ms; wjv[e] = mj;
#pragma unroll
    for (int s = 0; s < NS; s++)
      if (jR[s] == mj) { scR[s] = -1e30f; jR[s] = 0x7fffffff; }
  }

  // softmax (redundant on all lanes)
  const float m0 = wsv[0];
  float ex[8], sum = 0.f;
#pragma unroll
  for (int r = 0; r < 8; r++) { ex[r] = expf(wsv[r] - m0); sum += ex[r]; }
  const float inv = 1.f / sum;

  if (lane == 0) {
#pragma unroll
    for (int r = 0; r < 8; r++) {
      out_idx[(size_t)tok * 8 + r] = (float)wjv[r];
      out_w[(size_t)tok * 8 + r] = ex[r] * inv;
    }
  }

  // gather V: lane owns dims [lane*16, +16)
  f32x4 a0 = {0.f,0.f,0.f,0.f}, a1 = a0, a2 = a0, a3 = a0;
#pragma unroll
  for (int r = 0; r < 8; r++) {
    const float w = ex[r] * inv;
    const float* vp = V + (size_t)wjv[r] * 1024 + lane * 16;
    const f32x4 v0 = *(const f32x4*)(vp);
    const f32x4 v1 = *(const f32x4*)(vp + 4);
    const f32x4 v2 = *(const f32x4*)(vp + 8);
    const f32x4 v3 = *(const f32x4*)(vp + 12);
    a0 += w * v0; a1 += w * v1; a2 += w * v2; a3 += w * v3;
  }
  float* op = out + (size_t)tok * 1024 + lane * 16;
  *(f32x4*)(op)      = a0;
  *(f32x4*)(op + 4)  = a1;
  *(f32x4*)(op + 8)  = a2;
  *(f32x4*)(op + 12) = a3;
}

// ---------------------------------------------------------------------------
extern "C" void kernel_launch(void* const* d_in, const int* in_sizes, int n_in,
                              void* d_out, int out_size, void* d_ws, size_t ws_size,
                              hipStream_t stream) {
  const float* x  = (const float*)d_in[0];   // [2,4096,1024]
  const float* mw = (const float*)d_in[1];   // [2,4096,16]
  const float* cn = (const float*)d_in[2];   // [16,1024,64]
  const float* kK = (const float*)d_in[3];   // [16384,64]
  const float* kV = (const float*)d_in[4];   // [16384,1024]

  float* out  = (float*)d_out;               // 8192*1024
  float* oidx = out + (size_t)NTOK * D_MODEL;       // 8192*8
  float* ow   = oidx + (size_t)NTOK * TOPK;         // 8192*8

  // KS=2 needs: T 2x32MiB | Qf 2MiB | Qb 1MiB | Kb 2MiB = 72351744 B.
  // GM (32MiB) overlays T part 0 (dead after k1b). Falls back to KS=1.
  const size_t TSZ = (size_t)8192 * 1024 * 4;
  const int KS = (ws_size >= 2 * TSZ + 2097152 + 1048576 + 2097152) ? 2 : 1;
  const size_t tailOff = (size_t)KS * TSZ;

  float* T = (float*)d_ws;
  unsigned short* GM = (unsigned short*)d_ws;
  float* Qf = (float*)((char*)d_ws + tailOff);
  unsigned short* Qb = (unsigned short*)((char*)d_ws + tailOff + 2097152);
  unsigned short* Kb = (unsigned short*)((char*)d_ws + tailOff + 3145728);

  k1_gemm<<<512 * KS, 256, 0, stream>>>(x, cn, T, 1024 / KS);
  k1b_weight<<<2048, 256, 0, stream>>>(T, mw, Qf, Qb, KS);
  k1c_cvt<<<1024, 256, 0, stream>>>(kK, Kb);
  k2s_screen<<<2048, 256, 0, stream>>>(Qb, Kb, GM);
  k2b_select<<<2048, 256, 0, stream>>>(Qf, kK, kV, GM, out, oidx, ow);

  (void)in_sizes; (void)n_in; (void)out_size; (void)ws_size;
}

// Round 7
// 418.888 us; speedup vs baseline: 1.2022x; 1.0312x over previous
//
#include <hip/hip_runtime.h>
#include <hip/hip_bf16.h>

#define D_MODEL 1024
#define RANK 64
#define NCOMP 16
#define NKNOW 16384
#define TOPK 8
#define NTOK 8192   // B*S
#define MAXG 48     // candidate-group cap per token (groups of 8 j's)
#define NS 6        // rescore slots per lane (MAXG*8/64)

typedef __attribute__((ext_vector_type(4))) float f32x4;
typedef __attribute__((ext_vector_type(8))) short s16x8;

static __device__ __forceinline__ unsigned short f2bf(float f) {
  union { float f; unsigned u; } v; v.f = f;
  unsigned r = v.u + 0x7FFFu + ((v.u >> 16) & 1u);
  return (unsigned short)(r >> 16);
}
static __device__ __forceinline__ float bf2f(unsigned short h) {
  union { unsigned u; float f; } v; v.u = ((unsigned)h) << 16;
  return v.f;
}

// ---------------------------------------------------------------------------
// K1: T_part[ks] = X(8192 x kl) @ B(kl x 1024) over K rows [ks*kl, +kl),
// B[d][c] = cn[c>>6][d][c&63]. 128x128 tile, 256 threads, 8x8 micro, K-step 16.
// LDS swizzle: logical col c -> phys (c>>3)*12 + (c&7). 48B chunk pitch keeps
// 16B alignment for b128 and spreads read-start positions over 8 bank quads
// (2-way aliasing = free). Proven in round 5 (exact-f32 selection fidelity).
// ---------------------------------------------------------------------------
__global__ __launch_bounds__(256) void k1_gemm(const float* __restrict__ X,
                                               const float* __restrict__ CN,
                                               float* __restrict__ T,
                                               int kl) {
  __shared__ float As[16][192];
  __shared__ float Bs[16][192];
  const int bid = blockIdx.x & 511;
  const int ks = blockIdx.x >> 9;       // K-part
  const int bx = bid & 7;               // col block 0..7
  const int by = bid >> 3;              // row block 0..63
  const int tid = threadIdx.x;
  const int tx = tid & 15, ty = tid >> 4;
  const int row0 = by * 128, col0 = bx * 128;
  const int kbeg = ks * kl, kend = kbeg + kl;
  T += (size_t)ks * (8192 * 1024);

  const int ar = tid >> 1;              // 0..127
  const int ac = (tid & 1) * 8;         // 0 or 8
  const float* Aptr = X + (size_t)(row0 + ar) * 1024 + ac;
  const int apc = (ar >> 3) * 12 + (ar & 7);   // phys col of row ar

  const int bd = tid >> 4;              // 0..15
  const int bc = (tid & 15) * 8;        // 0..120
  const float* Bptr = CN + (size_t)((col0 + bc) >> 6) * (1024 * 64) + bd * 64
                         + ((col0 + bc) & 63);
  const int bpc = (tid & 15) * 12;      // phys col of chunk

  float acc[8][8] = {};

  f32x4 a0 = *(const f32x4*)(Aptr + kbeg);
  f32x4 a1 = *(const f32x4*)(Aptr + kbeg + 4);
  f32x4 b0 = *(const f32x4*)(Bptr + (size_t)kbeg * 64);
  f32x4 b1 = *(const f32x4*)(Bptr + (size_t)kbeg * 64 + 4);

  for (int k0 = kbeg; k0 < kend; k0 += 16) {
    __syncthreads();
#pragma unroll
    for (int j = 0; j < 4; j++) {
      As[ac + j][apc] = a0[j];
      As[ac + 4 + j][apc] = a1[j];
    }
    *(f32x4*)&Bs[bd][bpc] = b0;
    *(f32x4*)&Bs[bd][bpc + 4] = b1;
    __syncthreads();
    if (k0 + 16 < kend) {
      a0 = *(const f32x4*)(Aptr + k0 + 16);
      a1 = *(const f32x4*)(Aptr + k0 + 16 + 4);
      b0 = *(const f32x4*)(Bptr + (size_t)(k0 + 16) * 64);
      b1 = *(const f32x4*)(Bptr + (size_t)(k0 + 16) * 64 + 4);
    }
#pragma unroll
    for (int d = 0; d < 16; d++) {
      const f32x4 av0 = *(const f32x4*)&As[d][ty * 12];
      const f32x4 av1 = *(const f32x4*)&As[d][ty * 12 + 4];
      const f32x4 bv0 = *(const f32x4*)&Bs[d][tx * 12];
      const f32x4 bv1 = *(const f32x4*)&Bs[d][tx * 12 + 4];
#pragma unroll
      for (int i = 0; i < 4; i++) {
#pragma unroll
        for (int j = 0; j < 4; j++) {
          acc[i][j]         = fmaf(av0[i], bv0[j], acc[i][j]);
          acc[i][j + 4]     = fmaf(av0[i], bv1[j], acc[i][j + 4]);
          acc[i + 4][j]     = fmaf(av1[i], bv0[j], acc[i + 4][j]);
          acc[i + 4][j + 4] = fmaf(av1[i], bv1[j], acc[i + 4][j + 4]);
        }
      }
    }
  }
#pragma unroll
  for (int i = 0; i < 8; i++) {
    float* op = T + (size_t)(row0 + ty * 8 + i) * 1024 + col0 + tx * 8;
    *(f32x4*)op = *(f32x4*)&acc[i][0];
    *(f32x4*)(op + 4) = *(f32x4*)&acc[i][4];
  }
}

// ---------------------------------------------------------------------------
// K1b: Q[tok][r] = sum_n mw[tok][n] * (T0+T1)[tok][n*64+r]; emit bf16 copy.
// ---------------------------------------------------------------------------
__global__ __launch_bounds__(256) void k1b_weight(const float* __restrict__ T,
                                                  const float* __restrict__ MW,
                                                  float* __restrict__ Qf,
                                                  unsigned short* __restrict__ Qb,
                                                  int kparts) {
  const int gid = blockIdx.x * 256 + threadIdx.x;  // 0..524287
  const int tok = gid >> 6, r = gid & 63;
  float q = 0.f;
#pragma unroll
  for (int n = 0; n < 16; n++) {
    float tv = T[(size_t)tok * 1024 + n * 64 + r];
    if (kparts == 2)
      tv += T[(size_t)(8192 * 1024) + (size_t)tok * 1024 + n * 64 + r];
    q = fmaf(MW[tok * 16 + n], tv, q);
  }
  Qf[gid] = q;
  Qb[gid] = f2bf(q);
}

// ---------------------------------------------------------------------------
// K1c: Kb = bf16(knowledge_K)
// ---------------------------------------------------------------------------
__global__ __launch_bounds__(256) void k1c_cvt(const float* __restrict__ Kf,
                                               unsigned short* __restrict__ Kb) {
  const int gid = blockIdx.x * 256 + threadIdx.x;  // one per 4 elems
  f32x4 v = *(const f32x4*)(Kf + (size_t)gid * 4);
  unsigned short o0 = f2bf(v[0]), o1 = f2bf(v[1]), o2 = f2bf(v[2]), o3 = f2bf(v[3]);
  unsigned long long pack = (unsigned long long)o0 | ((unsigned long long)o1 << 16)
                          | ((unsigned long long)o2 << 32) | ((unsigned long long)o3 << 48);
  *(unsigned long long*)(Kb + (size_t)gid * 4) = pack;
}

// ---------------------------------------------------------------------------
// K2s: SINGLE screening pass. Per lane/tt: gm4 = max(c[0..3]); pair slices
// via shfl_xor(16) -> group-of-8 max; stash bf16 in LDS [tok][g] (pad 136),
// then coalesced 16B row writes to GM[tok][2048] at the end. GM layout
// (element g of token row = jsl*128 + 2*tt + (slice>>1)) matches k2b.
// ---------------------------------------------------------------------------
__global__ __launch_bounds__(256) void k2s_screen(
    const unsigned short* __restrict__ Qb,
    const unsigned short* __restrict__ Kb,
    unsigned short* __restrict__ GM) {
  __shared__ unsigned short sh[4][16][136];
  const int tid = threadIdx.x;
  const int wv = tid >> 6, lane = tid & 63;
  const int gw = blockIdx.x * 4 + wv;     // 0..8191
  const int tg = gw >> 4;                 // token group 0..511
  const int jsl = gw & 15;                // j-slice 0..15
  const int tb = tg * 16;
  const int myTok = lane & 15;
  const int slice = lane >> 4;            // 0..3

  const s16x8 bf0 = *(const s16x8*)(Qb + (size_t)(tb + myTok) * 64 + slice * 8);
  const s16x8 bf1 = *(const s16x8*)(Qb + (size_t)(tb + myTok) * 64 + 32 + slice * 8);

  const int j0 = jsl * 1024;
  const unsigned short* ap0 = Kb + (size_t)(j0 + myTok) * 64 + slice * 8;
  s16x8 af0 = *(const s16x8*)(ap0);
  s16x8 af1 = *(const s16x8*)(ap0 + 32);
  const bool writer = (slice & 1) == 0;
  const int sub = slice >> 1;

  for (int tt = 0; tt < 64; ++tt) {
    f32x4 c = {0.f, 0.f, 0.f, 0.f};
    c = __builtin_amdgcn_mfma_f32_16x16x32_bf16(af0, bf0, c, 0, 0, 0);
    c = __builtin_amdgcn_mfma_f32_16x16x32_bf16(af1, bf1, c, 0, 0, 0);
    if (tt + 1 < 64) {
      const unsigned short* ap = ap0 + (size_t)(tt + 1) * 16 * 64;
      af0 = *(const s16x8*)(ap);
      af1 = *(const s16x8*)(ap + 32);
    }
    const float gm4 = fmaxf(fmaxf(c[0], c[1]), fmaxf(c[2], c[3]));
    const float gm8 = fmaxf(gm4, __shfl_xor(gm4, 16));
    if (writer) sh[wv][myTok][2 * tt + sub] = f2bf(gm8);
  }
  __syncthreads();
  // coalesced write: lane -> token (lane>>2), 4 x 16B chunks
  {
    const int t = lane >> 2, cb = (lane & 3) * 8;
    unsigned short* orow = GM + (size_t)(tb + t) * 2048 + jsl * 128;
#pragma unroll
    for (int ch = 0; ch < 4; ch++)
      *(s16x8*)(orow + cb + ch * 32) = *(const s16x8*)&sh[wv][t][cb + ch * 32];
  }
}

// ---------------------------------------------------------------------------
// K2b: one wave per token. Read 2048 group-maxima -> thr = 8th-largest
// lane-max - margin (>=8 groups guaranteed) -> compact candidate groups ->
// exact f32 rescore of <=MAXG*8 j's -> exact top-8 (desc score, asc idx) ->
// softmax -> gather V -> outputs.
// ---------------------------------------------------------------------------
__global__ __launch_bounds__(256) void k2b_select(
    const float* __restrict__ Qf, const float* __restrict__ Kf,
    const float* __restrict__ V, const unsigned short* __restrict__ GM,
    float* __restrict__ out, float* __restrict__ out_idx,
    float* __restrict__ out_w) {
  __shared__ float qsh[4][64];
  __shared__ int csh[4][MAXG];
  __shared__ int scnt[4];
  const int tid = threadIdx.x;
  const int wv = tid >> 6, lane = tid & 63;
  const int tok = blockIdx.x * 4 + wv;    // 0..8191

  if (lane == 0) scnt[wv] = 0;
  qsh[wv][lane] = Qf[(size_t)tok * 64 + lane];

  // load 32 group-maxima per lane: groups g = i*256 + lane*4 + e
  unsigned long long gv[8];
  const unsigned long long* gmp =
      (const unsigned long long*)(GM + (size_t)tok * 2048);
#pragma unroll
  for (int i = 0; i < 8; i++) gv[i] = gmp[i * 64 + lane];

  float lm = -1e30f;
#pragma unroll
  for (int i = 0; i < 8; i++)
#pragma unroll
    for (int e = 0; e < 4; e++)
      lm = fmaxf(lm, bf2f((unsigned short)(gv[i] >> (e * 16))));

  // 8th-largest of the 64 lane-maxima (ties drop together -> thr only lower)
  float v = lm, m8 = -1e30f;
#pragma unroll
  for (int e = 0; e < 8; e++) {
    float m = v;
#pragma unroll
    for (int d = 1; d < 64; d <<= 1) m = fmaxf(m, __shfl_xor(m, d));
    m8 = m;
    if (e < 7) v = (v == m) ? -1e30f : v;
  }
  const float thr = m8 - 0.04f;

  // compact candidate groups (order irrelevant: exact rescore decides)
#pragma unroll
  for (int i = 0; i < 8; i++) {
#pragma unroll
    for (int e = 0; e < 4; e++) {
      const float g = bf2f((unsigned short)(gv[i] >> (e * 16)));
      if (g >= thr) {
        const int s = atomicAdd(&scnt[wv], 1);
        if (s < MAXG) csh[wv][s] = i * 256 + lane * 4 + e;
      }
    }
  }
  int ng = scnt[wv];
  if (ng > MAXG) ng = MAXG;
  const int nj = ng * 8;

  // exact f32 rescore
  float scR[NS]; int jR[NS];
#pragma unroll
  for (int s = 0; s < NS; s++) {
    scR[s] = -1e30f; jR[s] = 0x7fffffff;
    if (s * 64 < nj) {                    // wave-uniform
      const int ci = s * 64 + lane;
      if (ci < nj) {
        const int j = csh[wv][ci >> 3] * 8 + (ci & 7);
        const float* kp = Kf + (size_t)j * 64;
        float acc = 0.f;
#pragma unroll
        for (int k = 0; k < 64; k += 4) {
          const f32x4 qv = *(const f32x4*)&qsh[wv][k];
          const f32x4 kv = *(const f32x4*)(kp + k);
          acc = fmaf(qv[0], kv[0], acc);
          acc = fmaf(qv[1], kv[1], acc);
          acc = fmaf(qv[2], kv[2], acc);
          acc = fmaf(qv[3], kv[3], acc);
        }
        scR[s] = acc * 0.125f; jR[s] = j;
      }
    }
  }

  // exact top-8 (desc score, asc idx)
  float wsv[8]; int wjv[8];
#pragma unroll
  for (int e = 0; e < 8; e++) {
    float ms = scR[0]; int mj = jR[0];
#pragma unroll
    for (int s = 1; s < NS; s++)
      if (scR[s] > ms || (scR[s] == ms && jR[s] < mj)) { ms = scR[s]; mj = jR[s]; }
#pragma unroll
    for (int d = 1; d < 64; d <<= 1) {
      const float rs = __shfl_xor(ms, d);
      const int rj = __shfl_xor(mj, d);
      if (rs > ms || (rs == ms && rj < mj)) { ms = rs; mj = rj; }
    }
    wsv[e] = ms; wjv[e] = mj;
#pragma unroll
    for (int s = 0; s < NS; s++)
      if (jR[s] == mj) { scR[s] = -1e30f; jR[s] = 0x7fffffff; }
  }

  // softmax (redundant on all lanes)
  const float m0 = wsv[0];
  float ex[8], sum = 0.f;
#pragma unroll
  for (int r = 0; r < 8; r++) { ex[r] = expf(wsv[r] - m0); sum += ex[r]; }
  const float inv = 1.f / sum;

  if (lane == 0) {
#pragma unroll
    for (int r = 0; r < 8; r++) {
      out_idx[(size_t)tok * 8 + r] = (float)wjv[r];
      out_w[(size_t)tok * 8 + r] = ex[r] * inv;
    }
  }

  // gather V: lane owns dims [lane*16, +16)
  f32x4 a0 = {0.f,0.f,0.f,0.f}, a1 = a0, a2 = a0, a3 = a0;
#pragma unroll
  for (int r = 0; r < 8; r++) {
    const float w = ex[r] * inv;
    const float* vp = V + (size_t)wjv[r] * 1024 + lane * 16;
    const f32x4 v0 = *(const f32x4*)(vp);
    const f32x4 v1 = *(const f32x4*)(vp + 4);
    const f32x4 v2 = *(const f32x4*)(vp + 8);
    const f32x4 v3 = *(const f32x4*)(vp + 12);
    a0 += w * v0; a1 += w * v1; a2 += w * v2; a3 += w * v3;
  }
  float* op = out + (size_t)tok * 1024 + lane * 16;
  *(f32x4*)(op)      = a0;
  *(f32x4*)(op + 4)  = a1;
  *(f32x4*)(op + 8)  = a2;
  *(f32x4*)(op + 12) = a3;
}

// ---------------------------------------------------------------------------
extern "C" void kernel_launch(void* const* d_in, const int* in_sizes, int n_in,
                              void* d_out, int out_size, void* d_ws, size_t ws_size,
                              hipStream_t stream) {
  const float* x  = (const float*)d_in[0];   // [2,4096,1024]
  const float* mw = (const float*)d_in[1];   // [2,4096,16]
  const float* cn = (const float*)d_in[2];   // [16,1024,64]
  const float* kK = (const float*)d_in[3];   // [16384,64]
  const float* kV = (const float*)d_in[4];   // [16384,1024]

  float* out  = (float*)d_out;               // 8192*1024
  float* oidx = out + (size_t)NTOK * D_MODEL;       // 8192*8
  float* ow   = oidx + (size_t)NTOK * TOPK;         // 8192*8

  // KS=2 needs: T 2x32MiB | Qf 2MiB | Qb 1MiB | Kb 2MiB = 72351744 B.
  // GM (32MiB) overlays T part 0 (dead after k1b). Falls back to KS=1.
  const size_t TSZ = (size_t)8192 * 1024 * 4;
  const int KS = (ws_size >= 2 * TSZ + 2097152 + 1048576 + 2097152) ? 2 : 1;
  const size_t tailOff = (size_t)KS * TSZ;

  float* T = (float*)d_ws;
  unsigned short* GM = (unsigned short*)d_ws;
  float* Qf = (float*)((char*)d_ws + tailOff);
  unsigned short* Qb = (unsigned short*)((char*)d_ws + tailOff + 2097152);
  unsigned short* Kb = (unsigned short*)((char*)d_ws + tailOff + 3145728);

  k1_gemm<<<512 * KS, 256, 0, stream>>>(x, cn, T, 1024 / KS);
  k1b_weight<<<2048, 256, 0, stream>>>(T, mw, Qf, Qb, KS);
  k1c_cvt<<<1024, 256, 0, stream>>>(kK, Kb);
  k2s_screen<<<2048, 256, 0, stream>>>(Qb, Kb, GM);
  k2b_select<<<2048, 256, 0, stream>>>(Qf, kK, kV, GM, out, oidx, ow);

  (void)in_sizes; (void)n_in; (void)out_size; (void)ws_size;
}